// Round 7
// baseline (234.892 us; speedup 1.0000x reference)
//
#include <hip/hip_runtime.h>
#include <stdint.h>

#define PP 196            // 14*14
#define BP 6272           // 32*196

typedef _Float16 half_t;
typedef half_t half8v __attribute__((ext_vector_type(8)));
typedef half_t half4v __attribute__((ext_vector_type(4)));
typedef half_t half2v __attribute__((ext_vector_type(2)));

// ---------------------------------------------------------------------------
// assign kernels (layers 1,2): nearest-centroid 4-bit indices, packed 8/u32.
// f32 SCREEN + f64 FIXUP (R7-proven): screen tracks best/second-best; iff any
// lane's gap < TAU the wave re-runs that codebook with the exact f64 formula.
// idx layout: idxp[cb/8][BP]
// ---------------------------------------------------------------------------

template <typename T>
__global__ __launch_bounds__(256) void assign_1x1(
    const T* __restrict__ in, const float* __restrict__ cents,
    uint32_t* __restrict__ idxp, int nchan) {
  __shared__ float  sf[8][16][4];     // screen rows (16 B, one b128)
  __shared__ double sd[8][16][6];     // [c2, c0..c3, pad]: 48 B rows
  const int chunk = blockIdx.y;
  const int t = threadIdx.x;
  for (int i = t; i < 512; i += 256) {
    float c = cents[(size_t)chunk * 512 + i];
    int cb = i >> 6, r = i & 63;      // r = k*4 + d
    sf[cb][r >> 2][r & 3] = c;
    sd[cb][r >> 2][1 + (r & 3)] = (double)c;
  }
  __syncthreads();
  if (t < 128) {
    int cb = t >> 4, k = t & 15;
    double s = 0.0;
#pragma unroll
    for (int d = 0; d < 4; d++) { double c = sd[cb][k][1 + d]; s += c * c; }
    sd[cb][k][0] = s;
  }
  __syncthreads();
  const int p = blockIdx.x * 256 + t;
  if (p >= BP) return;
  const unsigned b = (unsigned)p / 196u;
  const unsigned pr = (unsigned)p - b * 196u;
  const T* xb = in + ((size_t)b * nchan + chunk * 32) * PP + pr;
  T xr[32];
#pragma unroll
  for (int i = 0; i < 32; i++) xr[i] = xb[(size_t)i * PP];
  float xs2[32];
#pragma unroll
  for (int i = 0; i < 32; i++) xs2[i] = 2.f * (float)xr[i];
  uint32_t word = 0;
#pragma unroll 1
  for (int cb = 0; cb < 8; cb++) {
    float best = 1e30f, sec = 1e30f; int bi = 0;
#pragma unroll
    for (int k = 0; k < 16; k++) {
      const float4 c = *(const float4*)&sf[cb][k][0];
      float dist = c.x * (c.x - xs2[cb * 4 + 0]);
      dist = fmaf(c.y, c.y - xs2[cb * 4 + 1], dist);
      dist = fmaf(c.z, c.z - xs2[cb * 4 + 2], dist);
      dist = fmaf(c.w, c.w - xs2[cb * 4 + 3], dist);
      if (dist < best) { sec = best; best = dist; bi = k; }
      else sec = fminf(sec, dist);
    }
    if (__any(sec - best < 2e-4f)) {
      double xv[4];
#pragma unroll
      for (int d = 0; d < 4; d++) xv[d] = (double)xr[cb * 4 + d];
      double bb = 1e300; int bi64 = 0;
#pragma unroll
      for (int k = 0; k < 16; k++) {
        double dot = 0.0;
#pragma unroll
        for (int d = 0; d < 4; d++) dot = fma(xv[d], sd[cb][k][1 + d], dot);
        double dist = sd[cb][k][0] - 2.0 * dot;
        if (dist < bb) { bb = dist; bi64 = k; }   // strict <: first-min
      }
      bi = bi64;
    }
    word |= (uint32_t)bi << (4 * cb);
  }
  idxp[(size_t)chunk * BP + p] = word;
}

// ---------------------------------------------------------------------------
// assign_3x3 v2: screen reads a pre-rounded f32 copy (out1f) -- identical
// values to (float)v64 since accum1 writes out1f = (float)r -- halving the
// screen's L2 bytes and dropping 72 cvts/thread; the exact f64 inputs are
// reloaded ONLY inside the rare fixup branch. Neighbor offsets/masks hoisted
// out of the cb loop (they're cb-invariant).
// ---------------------------------------------------------------------------
__global__ __launch_bounds__(256) void assign_3x3(
    const double* __restrict__ in, const float* __restrict__ inf,
    const float* __restrict__ cents, uint32_t* __restrict__ idxp) {
  __shared__ float  sf[8][16][12];    // [c2f, c0..c8, pad, pad]: 48 B rows
  __shared__ double sd[8][16][10];    // [c2, c0..c8]: 80 B rows
  const int chunk = blockIdx.y;
  const int c0g = chunk * 8;
  const int t = threadIdx.x;
  for (int i = t; i < 1152; i += 256) {
    int cb = i / 144, r = i - cb * 144;
    int k = r / 9, d = r - k * 9;
    float c = cents[(size_t)(c0g + cb) * 144 + k * 9 + d];
    sf[cb][k][1 + d] = c;
    sd[cb][k][1 + d] = (double)c;
  }
  __syncthreads();
  if (t < 128) {
    int cb = t >> 4, k = t & 15;
    double s = 0.0;
    float s32 = 0.f;
#pragma unroll
    for (int d = 0; d < 9; d++) {
      double c = sd[cb][k][1 + d]; s += c * c;
      float cf = sf[cb][k][1 + d]; s32 += cf * cf;
    }
    sd[cb][k][0] = s;
    sf[cb][k][0] = s32;
  }
  __syncthreads();
  const int p = blockIdx.x * 256 + t;
  if (p >= BP) return;
  const unsigned b = (unsigned)p / 196u;
  const unsigned pr = (unsigned)p - b * 196u;
  const int oh = pr / 14, ow = pr - oh * 14;
  // hoisted 3x3 neighborhood (cb-invariant)
  int  noff[9]; bool nok[9];
#pragma unroll
  for (int r = 0; r < 3; r++) {
#pragma unroll
    for (int cc = 0; cc < 3; cc++) {
      int hh = oh + r - 1, ww = ow + cc - 1;
      nok[r * 3 + cc] = (hh >= 0) & (hh < 14) & (ww >= 0) & (ww < 14);
      noff[r * 3 + cc] = hh * 14 + ww;
    }
  }
  uint32_t word = 0;
#pragma unroll 1
  for (int cb = 0; cb < 8; cb++) {
    const float* basef = inf + ((size_t)b * 256 + (c0g + cb)) * PP;
    float v32[9];
#pragma unroll
    for (int i = 0; i < 9; i++) v32[i] = nok[i] ? basef[noff[i]] : 0.f;
    float best = 1e30f, sec = 1e30f; int bi = 0;
#pragma unroll
    for (int k = 0; k < 16; k++) {
      const float4 cA = *(const float4*)&sf[cb][k][0];  // c2f,c0,c1,c2
      const float4 cB = *(const float4*)&sf[cb][k][4];  // c3..c6
      const float4 cC = *(const float4*)&sf[cb][k][8];  // c7,c8,pad,pad
      float dot = v32[0] * cA.y;
      dot = fmaf(v32[1], cA.z, dot);
      dot = fmaf(v32[2], cA.w, dot);
      dot = fmaf(v32[3], cB.x, dot);
      dot = fmaf(v32[4], cB.y, dot);
      dot = fmaf(v32[5], cB.z, dot);
      dot = fmaf(v32[6], cB.w, dot);
      dot = fmaf(v32[7], cC.x, dot);
      dot = fmaf(v32[8], cC.y, dot);
      float dist = fmaf(-2.f, dot, cA.x);
      if (dist < best) { sec = best; best = dist; bi = k; }
      else sec = fminf(sec, dist);
    }
    if (__any(sec - best < 4e-4f)) {
      const double* base = in + ((size_t)b * 256 + (c0g + cb)) * PP;
      double v64[9];
#pragma unroll
      for (int i = 0; i < 9; i++) v64[i] = nok[i] ? base[noff[i]] : 0.0;
      double bb = 1e300; int bi64 = 0;
#pragma unroll
      for (int k = 0; k < 16; k++) {
        double dot = 0.0;
#pragma unroll
        for (int d = 0; d < 9; d++) dot = fma(v64[d], sd[cb][k][1 + d], dot);
        double dist = sd[cb][k][0] - 2.0 * dot;
        if (dist < bb) { bb = dist; bi64 = k; }
      }
      bi = bi64;
    }
    word |= (uint32_t)bi << (4 * cb);
  }
  idxp[(size_t)chunk * BP + p] = word;
}

// ---------------------------------------------------------------------------
// accum v9 (f64-grade): R6's proven layout (XOR swizzle, coalesced staging,
// quad-f32 accumulation) + TWO POSITIONS PER THREAD. R6 counters: 42.9us vs
// ~39us LDS floor (reads 31.4 + staging 7.8). Gather instr count is the
// irreducible floor (f16 LUT upstream is precision-barred: argmin flips);
// v9 halves the OTHER LDS term: block = 128 pos x 4 quads (grid.x 49), one
// 16KB tile serves 128 positions -> staging loads/writes and barrier count
// per position halve. Acc state +8 f64 regs (short-lived staging regs stay
// within-iteration -- no R2-style spill pattern).
// outf: optional f32 copy of the output (layer 1 only) for assign_3x3's
// screen; written as (float)r == the rounding assign_3x3 formerly did.
// ---------------------------------------------------------------------------
template <int NCB, int NOUT, bool RELU, bool FUSE3, typename OutT>
__global__ __launch_bounds__(256) void accum_f64(
    const float* __restrict__ lut, const uint32_t* __restrict__ idxp,
    const float* __restrict__ scale, const float* __restrict__ bias,
    const float* __restrict__ c3cent, uint8_t* __restrict__ i3b,
    OutT* __restrict__ out, float* __restrict__ outf) {
  __shared__ float s_lut[4096];       // 16 KB: 16 cb x 16 k x 16 out
  __shared__ float  c3f[4][16][4];
  __shared__ float  c3c2f[4][16];
  __shared__ double c3d[4][16][4];
  __shared__ double c3c2d[4][16];
  const int t = threadIdx.x;
  const int lane = t & 63;
  const int q = t >> 6;                 // channel quad 0..3 (wave id)
  const int p0 = blockIdx.x * 128 + lane;   // 49*128 = 6272 = BP exactly
  const int p1 = p0 + 64;
  const int o_base = blockIdx.y * 16;
  if (FUSE3 && t < 64) {
    int cb_l = t >> 4, k = t & 15;
    const float4 cf = *(const float4*)(c3cent + ((size_t)(blockIdx.y * 4 + cb_l)) * 64 + k * 4);
    c3f[cb_l][k][0] = cf.x; c3f[cb_l][k][1] = cf.y;
    c3f[cb_l][k][2] = cf.z; c3f[cb_l][k][3] = cf.w;
    double d0 = (double)cf.x, d1 = (double)cf.y, d2 = (double)cf.z, d3 = (double)cf.w;
    c3d[cb_l][k][0] = d0; c3d[cb_l][k][1] = d1;
    c3d[cb_l][k][2] = d2; c3d[cb_l][k][3] = d3;
    double s = 0.0; s += d0 * d0; s += d1 * d1; s += d2 * d2; s += d3 * d3;
    c3c2d[cb_l][k] = s;
    float s32 = 0.f; s32 += cf.x * cf.x; s32 += cf.y * cf.y;
    s32 += cf.z * cf.z; s32 += cf.w * cf.w;
    c3c2f[cb_l][k] = s32;
  }
  // staging ownership (coalesced source): thread t owns cb=(t>>6)+4j,
  // q_s = t&3, k = (t>>2)&15; 4 consecutive lanes = 64B contiguous of one row.
  const float* src = lut + ((size_t)(t >> 6) * 16 + ((t >> 2) & 15)) * NOUT
                         + o_base + (t & 3) * 4;
  const int kk = (t >> 2) & 15, qs = t & 3;
  const int sslot = (t >> 6) * 64 + qs * 16 + (kk ^ (2 * qs));
  const int q2 = q * 2;               // wave-uniform gather swizzle term
  double aA0 = 0, aA1 = 0, aA2 = 0, aA3 = 0;
  double aB0 = 0, aB1 = 0, aB2 = 0, aB3 = 0;
  constexpr int NCHUNK = NCB / 16;
  for (int ch = 0; ch < NCHUNK; ch++) {
    __syncthreads();               // prior chunk's gathers done before overwrite
    uint32_t wA0 = idxp[(size_t)(ch * 2) * BP + p0];
    uint32_t wA1 = idxp[(size_t)(ch * 2 + 1) * BP + p0];
    uint32_t wB0 = idxp[(size_t)(ch * 2) * BP + p1];
    uint32_t wB1 = idxp[(size_t)(ch * 2 + 1) * BP + p1];
    {
      const float* g = src + (size_t)(ch * 256) * NOUT;
#pragma unroll
      for (int j = 0; j < 4; j++) {
        float4 v = *(const float4*)(g + (size_t)(64 * j) * NOUT);
        *(float4*)(s_lut + (sslot + 256 * j) * 4) = v;
      }
    }
    __syncthreads();               // chunk published
    const float* buf = s_lut + q * 64;
#pragma unroll
    for (int jq = 0; jq < 4; jq++) {   // cb quad (4jq .. 4jq+3)
      const int cbb = 4 * jq * 256;
      uint32_t ua = (jq < 2) ? wA0 : wA1;
      uint32_t ub = (jq < 2) ? wB0 : wB1;
      int sh = (jq & 1) * 16;
      {
        int i0 = (int)((ua >> sh) & 15u);
        int i1 = (int)((ua >> (sh + 4)) & 15u);
        int i2 = (int)((ua >> (sh + 8)) & 15u);
        int i3 = (int)((ua >> (sh + 12)) & 15u);
        const float4 va = *(const float4*)(buf + cbb       + (i0 ^ q2) * 4);
        const float4 vb = *(const float4*)(buf + cbb + 256 + (i1 ^ q2) * 4);
        const float4 vc = *(const float4*)(buf + cbb + 512 + (i2 ^ q2) * 4);
        const float4 vd = *(const float4*)(buf + cbb + 768 + (i3 ^ q2) * 4);
        float s0 = (va.x + vb.x) + (vc.x + vd.x);
        float s1 = (va.y + vb.y) + (vc.y + vd.y);
        float s2 = (va.z + vb.z) + (vc.z + vd.z);
        float s3 = (va.w + vb.w) + (vc.w + vd.w);
        aA0 += (double)s0; aA1 += (double)s1; aA2 += (double)s2; aA3 += (double)s3;
      }
      {
        int i0 = (int)((ub >> sh) & 15u);
        int i1 = (int)((ub >> (sh + 4)) & 15u);
        int i2 = (int)((ub >> (sh + 8)) & 15u);
        int i3 = (int)((ub >> (sh + 12)) & 15u);
        const float4 va = *(const float4*)(buf + cbb       + (i0 ^ q2) * 4);
        const float4 vb = *(const float4*)(buf + cbb + 256 + (i1 ^ q2) * 4);
        const float4 vc = *(const float4*)(buf + cbb + 512 + (i2 ^ q2) * 4);
        const float4 vd = *(const float4*)(buf + cbb + 768 + (i3 ^ q2) * 4);
        float s0 = (va.x + vb.x) + (vc.x + vd.x);
        float s1 = (va.y + vb.y) + (vc.y + vd.y);
        float s2 = (va.z + vb.z) + (vc.z + vd.z);
        float s3 = (va.w + vb.w) + (vc.w + vd.w);
        aB0 += (double)s0; aB1 += (double)s1; aB2 += (double)s2; aB3 += (double)s3;
      }
    }
  }
  const int o = o_base + q * 4;
  const float4 sc = *(const float4*)(scale + o);
  const float4 bs = *(const float4*)(bias + o);
#pragma unroll
  for (int pi = 0; pi < 2; pi++) {
    const int p = pi ? p1 : p0;
    double a0 = pi ? aB0 : aA0;
    double a1 = pi ? aB1 : aA1;
    double a2 = pi ? aB2 : aA2;
    double a3 = pi ? aB3 : aA3;
    const unsigned b = (unsigned)p / 196u;
    const unsigned pr = (unsigned)p - b * 196u;
    double r0 = a0 * (double)sc.x + (double)bs.x;
    double r1 = a1 * (double)sc.y + (double)bs.y;
    double r2 = a2 * (double)sc.z + (double)bs.z;
    double r3 = a3 * (double)sc.w + (double)bs.w;
    if (RELU) {
      r0 = fmax(r0, 0.0); r1 = fmax(r1, 0.0);
      r2 = fmax(r2, 0.0); r3 = fmax(r3, 0.0);
    }
    if (FUSE3) {
      // layer-3 assignment for codebook cb3 = blockIdx.y*4 + q
      const int cb_l = q;
      float x0 = (float)r0, x1 = (float)r1, x2 = (float)r2, x3 = (float)r3;
      float best = 1e30f, sec = 1e30f; int bi = 0;
#pragma unroll
      for (int k = 0; k < 16; k++) {
        const float4 c = *(const float4*)&c3f[cb_l][k][0];
        float dot = x0 * c.x;
        dot = fmaf(x1, c.y, dot);
        dot = fmaf(x2, c.z, dot);
        dot = fmaf(x3, c.w, dot);
        float dist = fmaf(-2.f, dot, c3c2f[cb_l][k]);
        if (dist < best) { sec = best; best = dist; bi = k; }
        else sec = fminf(sec, dist);
      }
      if (__any(sec - best < 1e-3f)) {
        double bb = 1e300; int bi64 = 0;
#pragma unroll
        for (int k = 0; k < 16; k++) {
          double dot = 0.0;
          dot = fma(r0, c3d[cb_l][k][0], dot);
          dot = fma(r1, c3d[cb_l][k][1], dot);
          dot = fma(r2, c3d[cb_l][k][2], dot);
          dot = fma(r3, c3d[cb_l][k][3], dot);
          double dist = c3c2d[cb_l][k] - 2.0 * dot;
          if (dist < bb) { bb = dist; bi64 = k; }   // strict <: first-min
        }
        bi = bi64;
      }
      // transposed: i3b[chunk16][p][16]  (chunk16 = cb3>>4, byte = cb3&15)
      i3b[((size_t)(blockIdx.y >> 2) * BP + p) * 16 + (blockIdx.y & 3) * 4 + q] =
          (uint8_t)bi;
    } else {
      OutT* op = out + ((size_t)b * NOUT + o) * PP + pr;
      op[0 * PP] = (OutT)r0; op[1 * PP] = (OutT)r1;
      op[2 * PP] = (OutT)r2; op[3 * PP] = (OutT)r3;
      if (outf) {
        float* ofp = outf + ((size_t)b * NOUT + o) * PP + pr;
        ofp[0 * PP] = (float)r0; ofp[1 * PP] = (float)r1;
        ofp[2 * PP] = (float)r2; ofp[3 * PP] = (float)r3;
      }
    }
  }
}

// ---------------------------------------------------------------------------
// accum3: final layer (no downstream argmin). f32 LUT -> f16 staged; packed
// v_pk_add_f16 inner loop, partials flushed to f32 every 8 codebooks.
// Staging: 4 lanes x float4 cover one LUT row's 16 useful cols (64B fully
// used); ds_write_b64 at row*80 + c*8 -> 8-lane group hits 4 quads, 2 lanes
// merged per 16B line = conflict-free. Rows 40 halfs (80B): gather bank-quad
// (5*idx+h)%8 bijective -> 2-way = free. Index read: lane-contiguous dwordx4
// per chunk from transposed i3b[ch][p][16].
// grid (49, 64), block 256 (4 waves): 128 positions x 16 channels.
// ---------------------------------------------------------------------------
__global__ __launch_bounds__(256) void accum3_f16(
    const float* __restrict__ lut, const uint8_t* __restrict__ i3b,
    const float* __restrict__ scale, const float* __restrict__ bias,
    const float* __restrict__ res, float* __restrict__ out) {
  __shared__ half_t s16[16 * 640];   // 20 KB
  const int t = threadIdx.x;
  const int lane = t & 63;
  const int wave = t >> 6;           // 0..3
  const int h = wave & 1;            // channel half (8 f16 ch)
  const int pg = wave >> 1;          // 0..1
  const int p = blockIdx.x * 128 + pg * 64 + lane;
  const int o_base = blockIdx.y * 16;
  // staging: slot s = t + 256j of 1024 -> row r = s>>2 (cb=r>>4, k=r&15),
  // col c = s&3 (floats 4c..4c+3 of the 16 useful cols)
  const int rs = t >> 2, cg = t & 3;
  const size_t cs = (size_t)16 * 16 * 1024;     // 16 cb per chunk (f32 elems)
  constexpr int NCHUNK = 4;
  float acc[8];
#pragma unroll
  for (int i = 0; i < 8; i++) acc[i] = 0.f;
  for (int ch = 0; ch < NCHUNK; ch++) {
    __syncthreads();
    const uint4 iw = *(const uint4*)(i3b + ((size_t)ch * BP + p) * 16);
    {
#pragma unroll
      for (int j = 0; j < 4; j++) {
        const int r = rs + 64 * j;
        const float4 v = *(const float4*)(lut + (size_t)ch * cs +
                                          (size_t)r * 1024 + o_base + cg * 4);
        half4v hv;
        hv[0] = (half_t)v.x; hv[1] = (half_t)v.y;
        hv[2] = (half_t)v.z; hv[3] = (half_t)v.w;
        *(half4v*)(s16 + (r >> 4) * 640 + (r & 15) * 40 + cg * 4) = hv;
      }
    }
    __syncthreads();
#pragma unroll
    for (int grp = 0; grp < 2; grp++) {   // 8 cb per f32 flush
      uint32_t wa = grp ? iw.z : iw.x;
      uint32_t wb = grp ? iw.w : iw.y;
      half2v p0 = 0, p1 = 0, p2 = 0, p3 = 0;
#pragma unroll
      for (int j = 0; j < 8; j++) {
        uint32_t w = (j < 4) ? wa : wb;
        int idx = (int)((w >> ((j & 3) * 8)) & 15u);
        int cb_l = grp * 8 + j;
        const half8v v = *(const half8v*)(s16 + cb_l * 640 + idx * 40 + h * 8);
        const half2v* vp = (const half2v*)&v;
        p0 += vp[0]; p1 += vp[1]; p2 += vp[2]; p3 += vp[3];
      }
      acc[0] += (float)p0[0]; acc[1] += (float)p0[1];
      acc[2] += (float)p1[0]; acc[3] += (float)p1[1];
      acc[4] += (float)p2[0]; acc[5] += (float)p2[1];
      acc[6] += (float)p3[0]; acc[7] += (float)p3[1];
    }
  }
  const unsigned b = (unsigned)p / 196u;
  const unsigned pr = (unsigned)p - b * 196u;
  const int o = o_base + h * 8;
  const float* rp = res + ((size_t)b * 1024 + o) * PP + pr;
  float* op = out + ((size_t)b * 1024 + o) * PP + pr;
#pragma unroll
  for (int i = 0; i < 8; i++) {
    float v = acc[i] * scale[o + i] + bias[o + i] + rp[(size_t)i * PP];
    op[(size_t)i * PP] = fmaxf(v, 0.f);
  }
}

// ---------------------------------------------------------------------------

extern "C" void kernel_launch(void* const* d_in, const int* in_sizes, int n_in,
                              void* d_out, int out_size, void* d_ws, size_t ws_size,
                              hipStream_t stream) {
  const float* x   = (const float*)d_in[0];   // [32,1024,14,14]
  const float* c1c = (const float*)d_in[1];
  const float* c1l = (const float*)d_in[2];
  const float* c1s = (const float*)d_in[3];
  const float* c1b = (const float*)d_in[4];
  const float* c2c = (const float*)d_in[5];
  const float* c2l = (const float*)d_in[6];
  const float* c2s = (const float*)d_in[7];
  const float* c2b = (const float*)d_in[8];
  const float* c3c = (const float*)d_in[9];
  const float* c3l = (const float*)d_in[10];  // [64,16,1024]
  const float* c3s = (const float*)d_in[11];
  const float* c3b = (const float*)d_in[12];

  const size_t sz_i1  = (size_t)32 * BP * 4;      // 802,816 B
  const size_t sz_i2  = (size_t)32 * BP * 4;
  const size_t sz_i3b = (size_t)BP * 64;          // 401,408 B (byte indices)
  const size_t sz_o64 = (size_t)BP * 256 * 8;     // 12.85 MB
  const size_t sz_o32 = (size_t)BP * 256 * 4;     // 6.42 MB (f32 screen copy)

  char* w = (char*)d_ws;
  uint32_t* i1 = (uint32_t*)w; w += sz_i1;
  uint32_t* i2 = (uint32_t*)w; w += sz_i2;
  uint8_t* i3b = (uint8_t*)w;  w += sz_i3b;
  double* out1;
  float* out1f;
  if (ws_size >= (size_t)(w - (char*)d_ws) + sz_o64 + sz_o32) {
    out1 = (double*)w; w += sz_o64;
    out1f = (float*)w;
  } else {
    // d_out (25.69 MB f32) holds out1 (12.85 MB f64) + out1f (6.42 MB f32);
    // accum3 (final) reads only i3b/x/c3l, then overwrites all of d_out.
    out1 = (double*)d_out;
    out1f = (float*)((char*)d_out + sz_o64);
  }

  const dim3 blkA(256), blkC(256);
  // layer 1: 1x1, 256 codebooks (dsub=4) over 1024 input channels
  assign_1x1<float><<<dim3(25, 32), blkA, 0, stream>>>(x, c1c, i1, 1024);
  accum_f64<256, 256, true, false, double><<<dim3(49, 16), blkC, 0, stream>>>(
      c1l, i1, c1s, c1b, nullptr, nullptr, out1, out1f);
  // layer 2: 3x3, 256 codebooks (dsub=9); epilogue fuses the layer-3 assign
  assign_3x3<<<dim3(25, 32), blkA, 0, stream>>>(out1, out1f, c2c, i2);
  accum_f64<256, 256, true, true, double><<<dim3(49, 16), blkC, 0, stream>>>(
      c2l, i2, c2s, c2b, c3c, i3b, nullptr, nullptr);
  // layer 3: 64 codebooks over 256 channels; fused residual + relu
  accum3_f16<<<dim3(49, 64), blkC, 0, stream>>>(
      c3l, i3b, c3s, c3b, x, (float*)d_out);
}

// Round 8
// 226.824 us; speedup vs baseline: 1.0356x; 1.0356x over previous
//
#include <hip/hip_runtime.h>
#include <stdint.h>

#define PP 196            // 14*14
#define BP 6272           // 32*196

typedef _Float16 half_t;
typedef half_t half8v __attribute__((ext_vector_type(8)));
typedef half_t half4v __attribute__((ext_vector_type(4)));
typedef half_t half2v __attribute__((ext_vector_type(2)));

// ---------------------------------------------------------------------------
// assign kernels (layers 1,2): nearest-centroid 4-bit indices, packed 8/u32.
// f32 SCREEN + f64 FIXUP: screen tracks best/second-best; iff any lane's gap
// < TAU the wave re-runs that codebook with exact f64 arithmetic.
// idx layout: idxp[cb/8][BP]
// ---------------------------------------------------------------------------

template <typename T>
__global__ __launch_bounds__(256) void assign_1x1(
    const T* __restrict__ in, const float* __restrict__ cents,
    uint32_t* __restrict__ idxp, int nchan) {
  __shared__ float  sf[8][16][4];     // screen rows (16 B, one b128)
  __shared__ double sd[8][16][6];     // [c2, c0..c3, pad]: 48 B rows
  const int chunk = blockIdx.y;
  const int t = threadIdx.x;
  for (int i = t; i < 512; i += 256) {
    float c = cents[(size_t)chunk * 512 + i];
    int cb = i >> 6, r = i & 63;      // r = k*4 + d
    sf[cb][r >> 2][r & 3] = c;
    sd[cb][r >> 2][1 + (r & 3)] = (double)c;
  }
  __syncthreads();
  if (t < 128) {
    int cb = t >> 4, k = t & 15;
    double s = 0.0;
#pragma unroll
    for (int d = 0; d < 4; d++) { double c = sd[cb][k][1 + d]; s += c * c; }
    sd[cb][k][0] = s;
  }
  __syncthreads();
  const int p = blockIdx.x * 256 + t;
  if (p >= BP) return;
  const unsigned b = (unsigned)p / 196u;
  const unsigned pr = (unsigned)p - b * 196u;
  const T* xb = in + ((size_t)b * nchan + chunk * 32) * PP + pr;
  T xr[32];
#pragma unroll
  for (int i = 0; i < 32; i++) xr[i] = xb[(size_t)i * PP];
  float xs2[32];
#pragma unroll
  for (int i = 0; i < 32; i++) xs2[i] = 2.f * (float)xr[i];
  uint32_t word = 0;
#pragma unroll 1
  for (int cb = 0; cb < 8; cb++) {
    float best = 1e30f, sec = 1e30f; int bi = 0;
#pragma unroll
    for (int k = 0; k < 16; k++) {
      const float4 c = *(const float4*)&sf[cb][k][0];
      float dist = c.x * (c.x - xs2[cb * 4 + 0]);
      dist = fmaf(c.y, c.y - xs2[cb * 4 + 1], dist);
      dist = fmaf(c.z, c.z - xs2[cb * 4 + 2], dist);
      dist = fmaf(c.w, c.w - xs2[cb * 4 + 3], dist);
      if (dist < best) { sec = best; best = dist; bi = k; }
      else sec = fminf(sec, dist);
    }
    if (__any(sec - best < 2e-4f)) {
      double xv[4];
#pragma unroll
      for (int d = 0; d < 4; d++) xv[d] = (double)xr[cb * 4 + d];
      double bb = 1e300; int bi64 = 0;
#pragma unroll
      for (int k = 0; k < 16; k++) {
        double dot = 0.0;
#pragma unroll
        for (int d = 0; d < 4; d++) dot = fma(xv[d], sd[cb][k][1 + d], dot);
        double dist = sd[cb][k][0] - 2.0 * dot;
        if (dist < bb) { bb = dist; bi64 = k; }   // strict <: first-min
      }
      bi = bi64;
    }
    word |= (uint32_t)bi << (4 * cb);
  }
  idxp[(size_t)chunk * BP + p] = word;
}

// ---------------------------------------------------------------------------
// assign_3x3 v3 (R8): input is the layer-1 output in F32 (the reference's own
// intermediate dtype -- our former f64 copy was strictly MORE precise than
// the tensor the reference argmins over). Screen reads the 9 f32 values;
// fixup upconverts those SAME registers to f64 (no reload, no second array).
// Index flips vs the f64-intermediate scheme require distance gaps < ~1e-6;
// absmax has sat at the accum3-f16 floor (0.03125) for 8 rounds -- no flip
// signature in this dataset. Neighbor offsets/masks hoisted (cb-invariant).
// ---------------------------------------------------------------------------
__global__ __launch_bounds__(256) void assign_3x3(
    const float* __restrict__ in, const float* __restrict__ cents,
    uint32_t* __restrict__ idxp) {
  __shared__ float  sf[8][16][12];    // [c2f, c0..c8, pad, pad]: 48 B rows
  __shared__ double sd[8][16][10];    // [c2, c0..c8]: 80 B rows
  const int chunk = blockIdx.y;
  const int c0g = chunk * 8;
  const int t = threadIdx.x;
  for (int i = t; i < 1152; i += 256) {
    int cb = i / 144, r = i - cb * 144;
    int k = r / 9, d = r - k * 9;
    float c = cents[(size_t)(c0g + cb) * 144 + k * 9 + d];
    sf[cb][k][1 + d] = c;
    sd[cb][k][1 + d] = (double)c;
  }
  __syncthreads();
  if (t < 128) {
    int cb = t >> 4, k = t & 15;
    double s = 0.0;
    float s32 = 0.f;
#pragma unroll
    for (int d = 0; d < 9; d++) {
      double c = sd[cb][k][1 + d]; s += c * c;
      float cf = sf[cb][k][1 + d]; s32 += cf * cf;
    }
    sd[cb][k][0] = s;
    sf[cb][k][0] = s32;
  }
  __syncthreads();
  const int p = blockIdx.x * 256 + t;
  if (p >= BP) return;
  const unsigned b = (unsigned)p / 196u;
  const unsigned pr = (unsigned)p - b * 196u;
  const int oh = pr / 14, ow = pr - oh * 14;
  // hoisted 3x3 neighborhood (cb-invariant)
  int  noff[9]; bool nok[9];
#pragma unroll
  for (int r = 0; r < 3; r++) {
#pragma unroll
    for (int cc = 0; cc < 3; cc++) {
      int hh = oh + r - 1, ww = ow + cc - 1;
      nok[r * 3 + cc] = (hh >= 0) & (hh < 14) & (ww >= 0) & (ww < 14);
      noff[r * 3 + cc] = hh * 14 + ww;
    }
  }
  uint32_t word = 0;
#pragma unroll 1
  for (int cb = 0; cb < 8; cb++) {
    const float* basef = in + ((size_t)b * 256 + (c0g + cb)) * PP;
    float v32[9];
#pragma unroll
    for (int i = 0; i < 9; i++) v32[i] = nok[i] ? basef[noff[i]] : 0.f;
    float best = 1e30f, sec = 1e30f; int bi = 0;
#pragma unroll
    for (int k = 0; k < 16; k++) {
      const float4 cA = *(const float4*)&sf[cb][k][0];  // c2f,c0,c1,c2
      const float4 cB = *(const float4*)&sf[cb][k][4];  // c3..c6
      const float4 cC = *(const float4*)&sf[cb][k][8];  // c7,c8,pad,pad
      float dot = v32[0] * cA.y;
      dot = fmaf(v32[1], cA.z, dot);
      dot = fmaf(v32[2], cA.w, dot);
      dot = fmaf(v32[3], cB.x, dot);
      dot = fmaf(v32[4], cB.y, dot);
      dot = fmaf(v32[5], cB.z, dot);
      dot = fmaf(v32[6], cB.w, dot);
      dot = fmaf(v32[7], cC.x, dot);
      dot = fmaf(v32[8], cC.y, dot);
      float dist = fmaf(-2.f, dot, cA.x);
      if (dist < best) { sec = best; best = dist; bi = k; }
      else sec = fminf(sec, dist);
    }
    if (__any(sec - best < 4e-4f)) {
      double bb = 1e300; int bi64 = 0;
#pragma unroll
      for (int k = 0; k < 16; k++) {
        double dot = 0.0;
#pragma unroll
        for (int d = 0; d < 9; d++)
          dot = fma((double)v32[d], sd[cb][k][1 + d], dot);
        double dist = sd[cb][k][0] - 2.0 * dot;
        if (dist < bb) { bb = dist; bi64 = k; }
      }
      bi = bi64;
    }
    word |= (uint32_t)bi << (4 * cb);
  }
  idxp[(size_t)chunk * BP + p] = word;
}

// ---------------------------------------------------------------------------
// accum v10 (f64-grade): EXACT R6 structure (the 42.9us/dispatch proven
// config: 1 pos/thread, grid 98x16, 36 VGPR, 42% occ, XOR swizzle slot =
// cb*64 + qs*16 + (k ^ 2qs), coalesced staging, quad-f32 accumulation,
// conflicts 25K). R7's 2-pos/thread (occ 42->18%) and dual f64+f32 output
// (WRITE 12.5->19.1MB) both reverted. Only change vs R6: layer-1 output is
// F32 (OutT=float) -- halves the out1 write (12.85->6.42MB).
// FUSE3 (layer 2): epilogue computes the layer-3 assignment in-register;
// i3b transposed [chunk16][p][16B] for accum3's lane-contiguous index read.
// ---------------------------------------------------------------------------
template <int NCB, int NOUT, bool RELU, bool FUSE3, typename OutT>
__global__ __launch_bounds__(256) void accum_f64(
    const float* __restrict__ lut, const uint32_t* __restrict__ idxp,
    const float* __restrict__ scale, const float* __restrict__ bias,
    const float* __restrict__ c3cent, uint8_t* __restrict__ i3b,
    OutT* __restrict__ out) {
  __shared__ float s_lut[4096];       // 16 KB: 16 cb x 16 k x 16 out
  __shared__ float  c3f[4][16][4];
  __shared__ float  c3c2f[4][16];
  __shared__ double c3d[4][16][4];
  __shared__ double c3c2d[4][16];
  const int t = threadIdx.x;
  const int lane = t & 63;
  const int q = t >> 6;                 // channel quad 0..3 (wave id)
  const int p = blockIdx.x * 64 + lane; // 98*64 = 6272 = BP exactly
  const int o_base = blockIdx.y * 16;
  if (FUSE3 && t < 64) {
    int cb_l = t >> 4, k = t & 15;
    const float4 cf = *(const float4*)(c3cent + ((size_t)(blockIdx.y * 4 + cb_l)) * 64 + k * 4);
    c3f[cb_l][k][0] = cf.x; c3f[cb_l][k][1] = cf.y;
    c3f[cb_l][k][2] = cf.z; c3f[cb_l][k][3] = cf.w;
    double d0 = (double)cf.x, d1 = (double)cf.y, d2 = (double)cf.z, d3 = (double)cf.w;
    c3d[cb_l][k][0] = d0; c3d[cb_l][k][1] = d1;
    c3d[cb_l][k][2] = d2; c3d[cb_l][k][3] = d3;
    double s = 0.0; s += d0 * d0; s += d1 * d1; s += d2 * d2; s += d3 * d3;
    c3c2d[cb_l][k] = s;
    float s32 = 0.f; s32 += cf.x * cf.x; s32 += cf.y * cf.y;
    s32 += cf.z * cf.z; s32 += cf.w * cf.w;
    c3c2f[cb_l][k] = s32;
  }
  // staging ownership (coalesced source): thread t owns cb=(t>>6)+4j,
  // q_s = t&3, k = (t>>2)&15; 4 consecutive lanes = 64B contiguous of one row.
  const float* src = lut + ((size_t)(t >> 6) * 16 + ((t >> 2) & 15)) * NOUT
                         + o_base + (t & 3) * 4;
  const int kk = (t >> 2) & 15, qs = t & 3;
  const int sslot = (t >> 6) * 64 + qs * 16 + (kk ^ (2 * qs));
  const int q2 = q * 2;               // wave-uniform gather swizzle term
  double a0 = 0, a1 = 0, a2 = 0, a3 = 0;
  constexpr int NCHUNK = NCB / 16;
  for (int ch = 0; ch < NCHUNK; ch++) {
    __syncthreads();               // prior chunk's gathers done before overwrite
    uint32_t w0 = idxp[(size_t)(ch * 2) * BP + p];
    uint32_t w1 = idxp[(size_t)(ch * 2 + 1) * BP + p];
    {
      const float* g = src + (size_t)(ch * 256) * NOUT;
#pragma unroll
      for (int j = 0; j < 4; j++) {
        float4 v = *(const float4*)(g + (size_t)(64 * j) * NOUT);
        *(float4*)(s_lut + (sslot + 256 * j) * 4) = v;
      }
    }
    __syncthreads();               // chunk published
    const float* buf = s_lut + q * 64;
#pragma unroll
    for (int jq = 0; jq < 4; jq++) {   // cb quad (4jq .. 4jq+3)
      const int cbb = 4 * jq * 256;
      uint32_t w = (jq < 2) ? w0 : w1;
      int sh = (jq & 1) * 16;
      int i0 = (int)((w >> sh) & 15u);
      int i1 = (int)((w >> (sh + 4)) & 15u);
      int i2 = (int)((w >> (sh + 8)) & 15u);
      int i3 = (int)((w >> (sh + 12)) & 15u);
      const float4 va = *(const float4*)(buf + cbb       + (i0 ^ q2) * 4);
      const float4 vb = *(const float4*)(buf + cbb + 256 + (i1 ^ q2) * 4);
      const float4 vc = *(const float4*)(buf + cbb + 512 + (i2 ^ q2) * 4);
      const float4 vd = *(const float4*)(buf + cbb + 768 + (i3 ^ q2) * 4);
      float s0 = (va.x + vb.x) + (vc.x + vd.x);
      float s1 = (va.y + vb.y) + (vc.y + vd.y);
      float s2 = (va.z + vb.z) + (vc.z + vd.z);
      float s3 = (va.w + vb.w) + (vc.w + vd.w);
      a0 += (double)s0; a1 += (double)s1; a2 += (double)s2; a3 += (double)s3;
    }
  }
  const unsigned b = (unsigned)p / 196u;
  const unsigned pr = (unsigned)p - b * 196u;
  const int o = o_base + q * 4;
  const float4 sc = *(const float4*)(scale + o);
  const float4 bs = *(const float4*)(bias + o);
  double r0 = a0 * (double)sc.x + (double)bs.x;
  double r1 = a1 * (double)sc.y + (double)bs.y;
  double r2 = a2 * (double)sc.z + (double)bs.z;
  double r3 = a3 * (double)sc.w + (double)bs.w;
  if (RELU) {
    r0 = fmax(r0, 0.0); r1 = fmax(r1, 0.0);
    r2 = fmax(r2, 0.0); r3 = fmax(r3, 0.0);
  }
  if (FUSE3) {
    // layer-3 assignment for codebook cb3 = blockIdx.y*4 + q (this thread's 4 ch)
    const int cb_l = q;
    float x0 = (float)r0, x1 = (float)r1, x2 = (float)r2, x3 = (float)r3;
    float best = 1e30f, sec = 1e30f; int bi = 0;
#pragma unroll
    for (int k = 0; k < 16; k++) {
      const float4 c = *(const float4*)&c3f[cb_l][k][0];
      float dot = x0 * c.x;
      dot = fmaf(x1, c.y, dot);
      dot = fmaf(x2, c.z, dot);
      dot = fmaf(x3, c.w, dot);
      float dist = fmaf(-2.f, dot, c3c2f[cb_l][k]);
      if (dist < best) { sec = best; best = dist; bi = k; }
      else sec = fminf(sec, dist);
    }
    if (__any(sec - best < 1e-3f)) {
      double bb = 1e300; int bi64 = 0;
#pragma unroll
      for (int k = 0; k < 16; k++) {
        double dot = 0.0;
        dot = fma(r0, c3d[cb_l][k][0], dot);
        dot = fma(r1, c3d[cb_l][k][1], dot);
        dot = fma(r2, c3d[cb_l][k][2], dot);
        dot = fma(r3, c3d[cb_l][k][3], dot);
        double dist = c3c2d[cb_l][k] - 2.0 * dot;
        if (dist < bb) { bb = dist; bi64 = k; }   // strict <: first-min
      }
      bi = bi64;
    }
    // transposed layout: i3b[chunk16][p][16]  (chunk16 = cb3>>4, byte = cb3&15)
    i3b[((size_t)(blockIdx.y >> 2) * BP + p) * 16 + (blockIdx.y & 3) * 4 + q] =
        (uint8_t)bi;
  } else {
    OutT* op = out + ((size_t)b * NOUT + o) * PP + pr;
    op[0 * PP] = (OutT)r0; op[1 * PP] = (OutT)r1;
    op[2 * PP] = (OutT)r2; op[3 * PP] = (OutT)r3;
  }
}

// ---------------------------------------------------------------------------
// accum3: final layer (no downstream argmin). f32 LUT -> f16 staged; packed
// v_pk_add_f16 inner loop, partials flushed to f32 every 8 codebooks.
// Staging: 4 lanes x float4 cover one LUT row's 16 useful cols (64B fully
// used); ds_write_b64 at row*80 + c*8 -> 8-lane group hits 4 quads, 2 lanes
// merged per 16B line = conflict-free. Rows 40 halfs (80B): gather bank-quad
// (5*idx+h)%8 bijective -> 2-way = free. Index read: lane-contiguous dwordx4
// per chunk from transposed i3b[ch][p][16].
// grid (49, 64), block 256 (4 waves): 128 positions x 16 channels.
// ---------------------------------------------------------------------------
__global__ __launch_bounds__(256) void accum3_f16(
    const float* __restrict__ lut, const uint8_t* __restrict__ i3b,
    const float* __restrict__ scale, const float* __restrict__ bias,
    const float* __restrict__ res, float* __restrict__ out) {
  __shared__ half_t s16[16 * 640];   // 20 KB
  const int t = threadIdx.x;
  const int lane = t & 63;
  const int wave = t >> 6;           // 0..3
  const int h = wave & 1;            // channel half (8 f16 ch)
  const int pg = wave >> 1;          // 0..1
  const int p = blockIdx.x * 128 + pg * 64 + lane;
  const int o_base = blockIdx.y * 16;
  // staging: slot s = t + 256j of 1024 -> row r = s>>2 (cb=r>>4, k=r&15),
  // col c = s&3 (floats 4c..4c+3 of the 16 useful cols)
  const int rs = t >> 2, cg = t & 3;
  const size_t cs = (size_t)16 * 16 * 1024;     // 16 cb per chunk (f32 elems)
  constexpr int NCHUNK = 4;
  float acc[8];
#pragma unroll
  for (int i = 0; i < 8; i++) acc[i] = 0.f;
  for (int ch = 0; ch < NCHUNK; ch++) {
    __syncthreads();
    const uint4 iw = *(const uint4*)(i3b + ((size_t)ch * BP + p) * 16);
    {
#pragma unroll
      for (int j = 0; j < 4; j++) {
        const int r = rs + 64 * j;
        const float4 v = *(const float4*)(lut + (size_t)ch * cs +
                                          (size_t)r * 1024 + o_base + cg * 4);
        half4v hv;
        hv[0] = (half_t)v.x; hv[1] = (half_t)v.y;
        hv[2] = (half_t)v.z; hv[3] = (half_t)v.w;
        *(half4v*)(s16 + (r >> 4) * 640 + (r & 15) * 40 + cg * 4) = hv;
      }
    }
    __syncthreads();
#pragma unroll
    for (int grp = 0; grp < 2; grp++) {   // 8 cb per f32 flush
      uint32_t wa = grp ? iw.z : iw.x;
      uint32_t wb = grp ? iw.w : iw.y;
      half2v p0 = 0, p1 = 0, p2 = 0, p3 = 0;
#pragma unroll
      for (int j = 0; j < 8; j++) {
        uint32_t w = (j < 4) ? wa : wb;
        int idx = (int)((w >> ((j & 3) * 8)) & 15u);
        int cb_l = grp * 8 + j;
        const half8v v = *(const half8v*)(s16 + cb_l * 640 + idx * 40 + h * 8);
        const half2v* vp = (const half2v*)&v;
        p0 += vp[0]; p1 += vp[1]; p2 += vp[2]; p3 += vp[3];
      }
      acc[0] += (float)p0[0]; acc[1] += (float)p0[1];
      acc[2] += (float)p1[0]; acc[3] += (float)p1[1];
      acc[4] += (float)p2[0]; acc[5] += (float)p2[1];
      acc[6] += (float)p3[0]; acc[7] += (float)p3[1];
    }
  }
  const unsigned b = (unsigned)p / 196u;
  const unsigned pr = (unsigned)p - b * 196u;
  const int o = o_base + h * 8;
  const float* rp = res + ((size_t)b * 1024 + o) * PP + pr;
  float* op = out + ((size_t)b * 1024 + o) * PP + pr;
#pragma unroll
  for (int i = 0; i < 8; i++) {
    float v = acc[i] * scale[o + i] + bias[o + i] + rp[(size_t)i * PP];
    op[(size_t)i * PP] = fmaxf(v, 0.f);
  }
}

// ---------------------------------------------------------------------------

extern "C" void kernel_launch(void* const* d_in, const int* in_sizes, int n_in,
                              void* d_out, int out_size, void* d_ws, size_t ws_size,
                              hipStream_t stream) {
  const float* x   = (const float*)d_in[0];   // [32,1024,14,14]
  const float* c1c = (const float*)d_in[1];
  const float* c1l = (const float*)d_in[2];
  const float* c1s = (const float*)d_in[3];
  const float* c1b = (const float*)d_in[4];
  const float* c2c = (const float*)d_in[5];
  const float* c2l = (const float*)d_in[6];
  const float* c2s = (const float*)d_in[7];
  const float* c2b = (const float*)d_in[8];
  const float* c3c = (const float*)d_in[9];
  const float* c3l = (const float*)d_in[10];  // [64,16,1024]
  const float* c3s = (const float*)d_in[11];
  const float* c3b = (const float*)d_in[12];

  const size_t sz_i1  = (size_t)32 * BP * 4;      // 802,816 B
  const size_t sz_i2  = (size_t)32 * BP * 4;
  const size_t sz_i3b = (size_t)BP * 64;          // 401,408 B (byte indices)
  const size_t sz_o32 = (size_t)BP * 256 * 4;     // 6.42 MB (f32 layer-1 out)

  char* w = (char*)d_ws;
  uint32_t* i1 = (uint32_t*)w; w += sz_i1;
  uint32_t* i2 = (uint32_t*)w; w += sz_i2;
  uint8_t* i3b = (uint8_t*)w;  w += sz_i3b;
  float* out1;
  if (ws_size >= (size_t)(w - (char*)d_ws) + sz_o32) {
    out1 = (float*)w;
  } else {
    // d_out (25.69 MB f32) holds out1 (6.42 MB f32) in its first quarter;
    // accum3 (final) reads only i3b/x/c3l, then overwrites all of d_out.
    out1 = (float*)d_out;
  }

  const dim3 blkA(256), blkC(256);
  // layer 1: 1x1, 256 codebooks (dsub=4) over 1024 input channels
  assign_1x1<float><<<dim3(25, 32), blkA, 0, stream>>>(x, c1c, i1, 1024);
  accum_f64<256, 256, true, false, float><<<dim3(98, 16), blkC, 0, stream>>>(
      c1l, i1, c1s, c1b, nullptr, nullptr, out1);
  // layer 2: 3x3, 256 codebooks (dsub=9); epilogue fuses the layer-3 assign
  assign_3x3<<<dim3(25, 32), blkA, 0, stream>>>(out1, c2c, i2);
  accum_f64<256, 256, true, true, float><<<dim3(98, 16), blkC, 0, stream>>>(
      c2l, i2, c2s, c2b, c3c, i3b, nullptr);
  // layer 3: 64 codebooks over 256 channels; fused residual + relu
  accum3_f16<<<dim3(49, 64), blkC, 0, stream>>>(
      c3l, i3b, c3s, c3b, x, (float*)d_out);
}